// Round 1
// baseline (332.559 us; speedup 1.0000x reference)
//
#include <hip/hip_runtime.h>
#include <hip/hip_bf16.h>
#include <stdint.h>

// Band-limited linear layer: y = x @ (mask*W)^T + bias
// x: [8192, 4096] f32, W: [4096, 4096] f32 (band |o-i|<=64), bias: [4096] f32.
// Block tile: 128 rows x 128 cols, K-slice = 256 inputs (band coverage),
// staged to LDS as bf16, 16x16x32 bf16 MFMA, fp32 accumulate.

constexpr int MROWS = 8192;
constexpr int NFEAT = 4096;
constexpr int KFEAT = 4096;
constexpr int DBAND = 64;

constexpr int BM = 128;
constexpr int BN = 128;
constexpr int BK = 64;                  // K chunk per staging step
constexpr int KT = BN + 2 * DBAND;      // 256 total K per col-block
constexpr int NCH = KT / BK;            // 4 chunks
constexpr int LDSW = BK + 8;            // 72 shorts: +16B pad -> 2-way (free) LDS aliasing

using bf16x8 = __attribute__((ext_vector_type(8))) short;  // 8 bf16 = 4 VGPRs
using f32x4  = __attribute__((ext_vector_type(4))) float;

__device__ __forceinline__ uint32_t pk2(float a, float b) {
    float2 t; t.x = a; t.y = b;
    __hip_bfloat162 h = __float22bfloat162_rn(t);
    union { __hip_bfloat162 h; uint32_t u; } cv;
    cv.h = h;
    return cv.u;  // low 16 bits = a, high = b (little-endian)
}

__global__ __launch_bounds__(256)
void band_linear_kernel(const float* __restrict__ x,
                        const float* __restrict__ w,
                        const float* __restrict__ bias,
                        float* __restrict__ y)
{
    __shared__ __align__(16) short sA[BM * LDSW];  // 18432 B
    __shared__ __align__(16) short sB[BN * LDSW];  // 18432 B

    const int tid  = threadIdx.x;
    const int lane = tid & 63;
    const int wave = tid >> 6;
    const int wm = wave & 1;     // wave row (64-row half)
    const int wn = wave >> 1;    // wave col (64-col half)

    const int cb = blockIdx.x;   // col block 0..31
    const int rb = blockIdx.y;   // row block 0..63
    const int row0 = rb * BM;
    const int col0 = cb * BN;
    const int i0 = col0 - DBAND; // first global input index of the K-slice

    // staging map: thread t -> tile row t>>1, k-half (t&1)*32 (32 floats each)
    const int srow = tid >> 1;
    const int koff = (tid & 1) * (BK / 2);

    const int gn  = col0 + srow;         // W output-feature row this thread stages
    const int wlo = gn - DBAND;
    const int whi = gn + DBAND;

    f32x4 acc[4][4];
    #pragma unroll
    for (int i = 0; i < 4; ++i)
        #pragma unroll
        for (int j = 0; j < 4; ++j)
            acc[i][j] = (f32x4){0.f, 0.f, 0.f, 0.f};

    const float* xsrc = x + (size_t)(row0 + srow) * KFEAT;
    const float* wsrc = w + (size_t)gn * KFEAT;

    for (int ch = 0; ch < NCH; ++ch) {
        const int kbase = i0 + ch * BK;
        // Edge chunks are fully out of range (64-aligned), uniform across block:
        if (kbase < 0 || kbase >= KFEAT) continue;

        // ---- stage x chunk -> sA (fp32 -> bf16)
        #pragma unroll
        for (int g = 0; g < 4; ++g) {
            const int kk = koff + g * 8;
            const float4 v0 = *(const float4*)(xsrc + kbase + kk);
            const float4 v1 = *(const float4*)(xsrc + kbase + kk + 4);
            uint4 p;
            p.x = pk2(v0.x, v0.y);
            p.y = pk2(v0.z, v0.w);
            p.z = pk2(v1.x, v1.y);
            p.w = pk2(v1.z, v1.w);
            *(uint4*)&sA[srow * LDSW + kk] = p;
        }

        // ---- stage masked W chunk -> sB (band mask applied algebraically)
        #pragma unroll
        for (int g = 0; g < 4; ++g) {
            const int kk = koff + g * 8;
            const int gk = kbase + kk;
            float4 v0 = *(const float4*)(wsrc + gk);
            float4 v1 = *(const float4*)(wsrc + gk + 4);
            v0.x = (gk + 0 >= wlo && gk + 0 <= whi) ? v0.x : 0.f;
            v0.y = (gk + 1 >= wlo && gk + 1 <= whi) ? v0.y : 0.f;
            v0.z = (gk + 2 >= wlo && gk + 2 <= whi) ? v0.z : 0.f;
            v0.w = (gk + 3 >= wlo && gk + 3 <= whi) ? v0.w : 0.f;
            v1.x = (gk + 4 >= wlo && gk + 4 <= whi) ? v1.x : 0.f;
            v1.y = (gk + 5 >= wlo && gk + 5 <= whi) ? v1.y : 0.f;
            v1.z = (gk + 6 >= wlo && gk + 6 <= whi) ? v1.z : 0.f;
            v1.w = (gk + 7 >= wlo && gk + 7 <= whi) ? v1.w : 0.f;
            uint4 p;
            p.x = pk2(v0.x, v0.y);
            p.y = pk2(v0.z, v0.w);
            p.z = pk2(v1.x, v1.y);
            p.w = pk2(v1.z, v1.w);
            *(uint4*)&sB[srow * LDSW + kk] = p;
        }

        __syncthreads();

        // ---- MFMA: 2 k-steps of 32, 4x4 fragment grid per wave
        #pragma unroll
        for (int s = 0; s < 2; ++s) {
            bf16x8 af[4], bfr[4];
            #pragma unroll
            for (int mf = 0; mf < 4; ++mf) {
                const int r = wm * 64 + mf * 16 + (lane & 15);
                af[mf] = *(const bf16x8*)&sA[r * LDSW + s * 32 + (lane >> 4) * 8];
            }
            #pragma unroll
            for (int nf = 0; nf < 4; ++nf) {
                const int r = wn * 64 + nf * 16 + (lane & 15);
                bfr[nf] = *(const bf16x8*)&sB[r * LDSW + s * 32 + (lane >> 4) * 8];
            }
            #pragma unroll
            for (int mf = 0; mf < 4; ++mf)
                #pragma unroll
                for (int nf = 0; nf < 4; ++nf)
                    acc[mf][nf] = __builtin_amdgcn_mfma_f32_16x16x32_bf16(
                        af[mf], bfr[nf], acc[mf][nf], 0, 0, 0);
        }

        __syncthreads();
    }

    // ---- epilogue: C/D layout col=lane&15, row=(lane>>4)*4+reg
    const int lquad = lane >> 4;
    const int lcol  = lane & 15;
    #pragma unroll
    for (int nf = 0; nf < 4; ++nf) {
        const int gc = col0 + wn * 64 + nf * 16 + lcol;
        const float bv = bias[gc];
        #pragma unroll
        for (int mf = 0; mf < 4; ++mf) {
            const int gr = row0 + wm * 64 + mf * 16 + lquad * 4;
            float* dst = y + (size_t)gr * NFEAT + gc;
            #pragma unroll
            for (int r2 = 0; r2 < 4; ++r2)
                dst[(size_t)r2 * NFEAT] = acc[mf][nf][r2] + bv;
        }
    }
}

extern "C" void kernel_launch(void* const* d_in, const int* in_sizes, int n_in,
                              void* d_out, int out_size, void* d_ws, size_t ws_size,
                              hipStream_t stream) {
    const float* x    = (const float*)d_in[0];
    const float* w    = (const float*)d_in[1];
    const float* bias = (const float*)d_in[2];
    // d_in[3] (mask) is not read: the band condition |o-i|<=64 is applied
    // algebraically during W staging (identical values).
    float* y = (float*)d_out;

    dim3 grid(NFEAT / BN, MROWS / BM);  // 32 x 64 = 2048 blocks
    band_linear_kernel<<<grid, 256, 0, stream>>>(x, w, bias, y);
}

// Round 2
// 300.071 us; speedup vs baseline: 1.1083x; 1.1083x over previous
//
#include <hip/hip_runtime.h>
#include <hip/hip_bf16.h>
#include <stdint.h>

// Band-limited linear layer: y = x @ (mask*W)^T + bias
// x: [8192, 4096] f32, W: [4096, 4096] f32 (band |o-i|<=64), bias: [4096] f32.
// R1: 512-thread blocks (8 waves, 64x32 per-wave tile -> acc 32 regs) +
// register prefetch of next K-chunk overlapping MFMA. Targets latency-bound
// profile from R0 (28% HBM, 27% occupancy, all pipes idle).

constexpr int MROWS = 8192;
constexpr int NFEAT = 4096;
constexpr int KFEAT = 4096;
constexpr int DBAND = 64;

constexpr int BM = 128;
constexpr int BN = 128;
constexpr int BK = 64;                  // K chunk per staging step
constexpr int NCH = (BN + 2 * DBAND) / BK;  // 4 chunks of 64 over the 256-wide slice
constexpr int LDSW = BK + 8;            // 72 shorts: +16B pad -> 2-way (free) aliasing

using bf16x8 = __attribute__((ext_vector_type(8))) short;  // 8 bf16 = 4 VGPRs
using f32x4  = __attribute__((ext_vector_type(4))) float;

__device__ __forceinline__ uint32_t pk2(float a, float b) {
    float2 t; t.x = a; t.y = b;
    __hip_bfloat162 h = __float22bfloat162_rn(t);
    union { __hip_bfloat162 h; uint32_t u; } cv;
    cv.h = h;
    return cv.u;  // low 16 = a, high 16 = b
}

__global__ __launch_bounds__(512)
void band_linear_kernel(const float* __restrict__ x,
                        const float* __restrict__ w,
                        const float* __restrict__ bias,
                        float* __restrict__ y)
{
    __shared__ __align__(16) short sA[BM * LDSW];  // 18432 B
    __shared__ __align__(16) short sB[BN * LDSW];  // 18432 B

    const int tid  = threadIdx.x;
    const int lane = tid & 63;
    const int wave = tid >> 6;      // 0..7
    const int wm = wave >> 2;       // row half (64 rows)
    const int wn = wave & 3;        // col quarter (32 cols)

    const int cb = blockIdx.x;      // col block 0..31
    const int rb = blockIdx.y;      // row block 0..63
    const int row0 = rb * BM;
    const int col0 = cb * BN;
    const int i0 = col0 - DBAND;    // first global input index of the K-slice

    // staging map: thread t -> tile row t>>2, 16-float span (t&3)*16
    const int srow = tid >> 2;           // 0..127
    const int koff = (tid & 3) * 16;     // 0,16,32,48

    const int gn  = col0 + srow;         // W output-feature row this thread stages
    const int wlo = gn - DBAND;
    const int whi = gn + DBAND;

    const float* xsrc = x + (size_t)(row0 + srow) * KFEAT + koff;
    const float* wsrc = w + (size_t)gn * KFEAT + koff;

    f32x4 acc[4][2];
    #pragma unroll
    for (int i = 0; i < 4; ++i)
        #pragma unroll
        for (int j = 0; j < 2; ++j)
            acc[i][j] = (f32x4){0.f, 0.f, 0.f, 0.f};

    float4 px[4], pw[4];  // prefetch registers (32 VGPRs)

    // uniform valid-chunk range (band edges are 64-aligned)
    int ch = (cb == 0) ? 1 : 0;
    const int che = (cb == (NFEAT / BN - 1)) ? (NCH - 1) : NCH;

    // issue chunk ch's global loads into px/pw
    {
        const int kb = i0 + ch * BK;
        #pragma unroll
        for (int g = 0; g < 4; ++g) {
            px[g] = *(const float4*)(xsrc + kb + g * 4);
            pw[g] = *(const float4*)(wsrc + kb + g * 4);
        }
    }

    while (true) {
        // ---- stage current chunk from regs into LDS (cvt + band mask)
        {
            const int kg = i0 + ch * BK + koff;
            uint4 pa0, pa1, pb0, pb1;
            pa0.x = pk2(px[0].x, px[0].y);  pa0.y = pk2(px[0].z, px[0].w);
            pa0.z = pk2(px[1].x, px[1].y);  pa0.w = pk2(px[1].z, px[1].w);
            pa1.x = pk2(px[2].x, px[2].y);  pa1.y = pk2(px[2].z, px[2].w);
            pa1.z = pk2(px[3].x, px[3].y);  pa1.w = pk2(px[3].z, px[3].w);
            float4 mv[4];
            #pragma unroll
            for (int g = 0; g < 4; ++g) {
                const int gk = kg + g * 4;
                float4 v = pw[g];
                v.x = (gk + 0 >= wlo && gk + 0 <= whi) ? v.x : 0.f;
                v.y = (gk + 1 >= wlo && gk + 1 <= whi) ? v.y : 0.f;
                v.z = (gk + 2 >= wlo && gk + 2 <= whi) ? v.z : 0.f;
                v.w = (gk + 3 >= wlo && gk + 3 <= whi) ? v.w : 0.f;
                mv[g] = v;
            }
            pb0.x = pk2(mv[0].x, mv[0].y);  pb0.y = pk2(mv[0].z, mv[0].w);
            pb0.z = pk2(mv[1].x, mv[1].y);  pb0.w = pk2(mv[1].z, mv[1].w);
            pb1.x = pk2(mv[2].x, mv[2].y);  pb1.y = pk2(mv[2].z, mv[2].w);
            pb1.z = pk2(mv[3].x, mv[3].y);  pb1.w = pk2(mv[3].z, mv[3].w);
            *(uint4*)&sA[srow * LDSW + koff]     = pa0;
            *(uint4*)&sA[srow * LDSW + koff + 8] = pa1;
            *(uint4*)&sB[srow * LDSW + koff]     = pb0;
            *(uint4*)&sB[srow * LDSW + koff + 8] = pb1;
        }

        __syncthreads();

        // ---- prefetch next chunk (flies during MFMA below)
        const bool more = (ch + 1) < che;
        if (more) {
            const int kb = i0 + (ch + 1) * BK;
            #pragma unroll
            for (int g = 0; g < 4; ++g) {
                px[g] = *(const float4*)(xsrc + kb + g * 4);
                pw[g] = *(const float4*)(wsrc + kb + g * 4);
            }
        }

        // ---- MFMA: 2 k-steps of 32, 4x2 fragment grid per wave
        #pragma unroll
        for (int s = 0; s < 2; ++s) {
            bf16x8 af[4], bfr[2];
            #pragma unroll
            for (int mf = 0; mf < 4; ++mf) {
                const int r = wm * 64 + mf * 16 + (lane & 15);
                af[mf] = *(const bf16x8*)&sA[r * LDSW + s * 32 + (lane >> 4) * 8];
            }
            #pragma unroll
            for (int nf = 0; nf < 2; ++nf) {
                const int r = wn * 32 + nf * 16 + (lane & 15);
                bfr[nf] = *(const bf16x8*)&sB[r * LDSW + s * 32 + (lane >> 4) * 8];
            }
            #pragma unroll
            for (int mf = 0; mf < 4; ++mf)
                #pragma unroll
                for (int nf = 0; nf < 2; ++nf)
                    acc[mf][nf] = __builtin_amdgcn_mfma_f32_16x16x32_bf16(
                        af[mf], bfr[nf], acc[mf][nf], 0, 0, 0);
        }

        if (!more) break;
        __syncthreads();
        ++ch;
    }

    // ---- epilogue: C/D layout col=lane&15, row=(lane>>4)*4+reg
    const int lquad = lane >> 4;
    const int lcol  = lane & 15;
    #pragma unroll
    for (int nf = 0; nf < 2; ++nf) {
        const int gc = col0 + wn * 32 + nf * 16 + lcol;
        const float bv = bias[gc];
        #pragma unroll
        for (int mf = 0; mf < 4; ++mf) {
            const int gr = row0 + wm * 64 + mf * 16 + lquad * 4;
            float* dst = y + (size_t)gr * NFEAT + gc;
            #pragma unroll
            for (int r2 = 0; r2 < 4; ++r2)
                dst[(size_t)r2 * NFEAT] = acc[mf][nf][r2] + bv;
        }
    }
}

extern "C" void kernel_launch(void* const* d_in, const int* in_sizes, int n_in,
                              void* d_out, int out_size, void* d_ws, size_t ws_size,
                              hipStream_t stream) {
    const float* x    = (const float*)d_in[0];
    const float* w    = (const float*)d_in[1];
    const float* bias = (const float*)d_in[2];
    // d_in[3] (mask) unused: band condition applied algebraically in staging.
    float* y = (float*)d_out;

    dim3 grid(NFEAT / BN, MROWS / BM);  // 32 x 64 = 2048 blocks
    band_linear_kernel<<<grid, 512, 0, stream>>>(x, w, bias, y);
}